// Round 1
// baseline (508.096 us; speedup 1.0000x reference)
//
#include <hip/hip_runtime.h>
#include <math.h>

// Problem constants (from setup_inputs)
constexpr int B   = 4;
constexpr int N   = 8192;
constexpr int M   = 2048;
constexpr int C1  = 128;
constexpr int C2  = 256;
constexpr int HCH = 256;   // H
constexpr int CIN = 384;   // C2 + C1
constexpr float BN_EPS = 1e-5f;
constexpr float SLOPE  = 0.2f;
constexpr float BN_CNT = (float)(B * N);   // BN reduces over (B, N)

// ---------------- zero stats ----------------
__global__ void k_zero(float* __restrict__ stats) {
  int i = blockIdx.x * blockDim.x + threadIdx.x;
  if (i < 1024) stats[i] = 0.f;
}

// ---------------- three_nn + inverse-distance weights ----------------
// grid: B*(N/64) blocks of 64 threads; xyz2 batch slice staged in LDS.
__global__ __launch_bounds__(64) void k_nn(const float* __restrict__ xyz1,
                                           const float* __restrict__ xyz2,
                                           float* __restrict__ wgt,
                                           int* __restrict__ idxo) {
  __shared__ float4 q[M];
  const int tid  = threadIdx.x;
  const int nblk = N / 64;                 // 128
  const int b    = blockIdx.x / nblk;
  const int n0   = (blockIdx.x % nblk) * 64;

  const float* src = xyz2 + (size_t)b * M * 3;
  for (int i = tid; i < M; i += 64) {
    float x = src[i*3+0], y = src[i*3+1], z = src[i*3+2];
    q[i] = make_float4(x, y, z, x*x + y*y + z*z);
  }
  __syncthreads();

  const int n = n0 + tid;
  const float* p = xyz1 + ((size_t)b * N + n) * 3;
  const float px = p[0], py = p[1], pz = p[2];
  const float n1 = px*px + py*py + pz*pz;

  float d0 = 3.4e38f, d1 = 3.4e38f, d2 = 3.4e38f;
  int   j0 = 0, j1 = 0, j2 = 0;
  for (int m = 0; m < M; ++m) {
    float4 c = q[m];
    float dot = px*c.x + py*c.y + pz*c.z;
    float d = fmaf(-2.f, dot, n1 + c.w);   // ||p||^2 + ||q||^2 - 2 p.q (ref formula)
    if (d < d2) {                           // strict < keeps lower index on ties (top_k semantics)
      if (d < d1) {
        if (d < d0) { d2 = d1; j2 = j1; d1 = d0; j1 = j0; d0 = d; j0 = m; }
        else        { d2 = d1; j2 = j1; d1 = d;  j1 = m; }
      } else        { d2 = d;  j2 = m; }
    }
  }
  d0 = fmaxf(d0, 1e-10f); d1 = fmaxf(d1, 1e-10f); d2 = fmaxf(d2, 1e-10f);
  float r0 = 1.f / d0, r1 = 1.f / d1, r2 = 1.f / d2;
  float s  = r0 + r1 + r2;
  size_t base = ((size_t)b * N + n) * 3;
  wgt[base+0] = r0 / s;  wgt[base+1] = r1 / s;  wgt[base+2] = r2 / s;
  idxo[base+0] = j0;     idxo[base+1] = j1;     idxo[base+2] = j2;
}

// ---------------- transpose points2: (B,C2,M) -> (B,M,C2) ----------------
__global__ __launch_bounds__(256) void k_tr(const float* __restrict__ P2,
                                            float* __restrict__ P2T) {
  __shared__ float t[32][33];
  const int b  = blockIdx.z;
  const int m0 = blockIdx.x * 32;
  const int c0 = blockIdx.y * 32;
  const int tx = threadIdx.x & 31;
  const int ty = threadIdx.x >> 5;        // 0..7
  const float* src = P2 + (size_t)b * C2 * M;
  #pragma unroll
  for (int j = 0; j < 4; ++j)
    t[ty + j*8][tx] = src[(size_t)(c0 + ty + j*8) * M + m0 + tx];
  __syncthreads();
  float* dst = P2T + (size_t)b * M * C2;
  #pragma unroll
  for (int j = 0; j < 4; ++j)
    dst[(size_t)(m0 + ty + j*8) * C2 + c0 + tx] = t[tx][ty + j*8];
}

// ---------------- interpolate (from P2T) + concat points1 -> X (B,CIN,N) ----------------
__global__ __launch_bounds__(256) void k_interp(const float* __restrict__ P2T,
                                                const float* __restrict__ points1,
                                                const float* __restrict__ wgt,
                                                const int* __restrict__ idx,
                                                float* __restrict__ X) {
  const int b = blockIdx.y;
  const int n = blockIdx.x * 256 + threadIdx.x;
  const size_t base = (size_t)b * N + n;
  const int i0 = idx[base*3+0], i1 = idx[base*3+1], i2 = idx[base*3+2];
  const float w0 = wgt[base*3+0], w1 = wgt[base*3+1], w2 = wgt[base*3+2];
  const float4* r0 = (const float4*)(P2T + ((size_t)b * M + i0) * C2);
  const float4* r1 = (const float4*)(P2T + ((size_t)b * M + i1) * C2);
  const float4* r2 = (const float4*)(P2T + ((size_t)b * M + i2) * C2);
  float* Xb = X + (size_t)b * CIN * N + n;
  #pragma unroll 4
  for (int c4 = 0; c4 < C2/4; ++c4) {
    float4 a0 = r0[c4], a1 = r1[c4], a2 = r2[c4];
    Xb[(size_t)(c4*4+0) * N] = w0*a0.x + w1*a1.x + w2*a2.x;
    Xb[(size_t)(c4*4+1) * N] = w0*a0.y + w1*a1.y + w2*a2.y;
    Xb[(size_t)(c4*4+2) * N] = w0*a0.z + w1*a1.z + w2*a2.z;
    Xb[(size_t)(c4*4+3) * N] = w0*a0.w + w1*a1.w + w2*a2.w;
  }
  const float* p1 = points1 + (size_t)b * C1 * N + n;
  float* Xc = Xb + (size_t)C2 * N;
  #pragma unroll 4
  for (int c = 0; c < C1; ++c) Xc[(size_t)c * N] = p1[(size_t)c * N];
}

// ---------------- f32 tiled GEMM: Y(B,HCH,N) = W(HCH,K) @ Xin(B,K,N) + bias ----------------
// XFORM: apply per-channel BN affine + LeakyReLU (coef[c]=a, coef[256+c]=b) to Xin on load.
// Epilogue accumulates per-channel sum / sumsq into stats[0..255] / stats[256..511].
template <int K, bool XFORM>
__global__ __launch_bounds__(256) void k_gemm(const float* __restrict__ Wm,
                                              const float* __restrict__ bias,
                                              const float* __restrict__ Xin,
                                              const float* __restrict__ coef,
                                              float* __restrict__ Yout,
                                              float* __restrict__ stats) {
  constexpr int BK = 32;
  __shared__ float Wt[BK][64];
  __shared__ float Xt[BK][64];
  const int tid = threadIdx.x;
  const int tx = tid & 15, ty = tid >> 4;
  const int n0 = blockIdx.x * 64;
  const int o0 = blockIdx.y * 64;
  const int b  = blockIdx.z;
  const float* Xb = Xin + (size_t)b * K * N;

  float acc[4][4] = {};

  for (int k0 = 0; k0 < K; k0 += BK) {
    { // W tile 64x32, transpose into Wt[k][o]
      const int o  = tid >> 2;
      const int kk = (tid & 3) * 8;
      const float* wp = Wm + (size_t)(o0 + o) * K + k0 + kk;
      float4 wv0 = *(const float4*)(wp);
      float4 wv1 = *(const float4*)(wp + 4);
      Wt[kk+0][o] = wv0.x; Wt[kk+1][o] = wv0.y; Wt[kk+2][o] = wv0.z; Wt[kk+3][o] = wv0.w;
      Wt[kk+4][o] = wv1.x; Wt[kk+5][o] = wv1.y; Wt[kk+6][o] = wv1.z; Wt[kk+7][o] = wv1.w;
    }
    { // X tile 32x64
      const int k  = tid >> 3;
      const int nn = (tid & 7) * 8;
      const float* xp = Xb + (size_t)(k0 + k) * N + n0 + nn;
      float4 x0 = *(const float4*)(xp);
      float4 x1 = *(const float4*)(xp + 4);
      if constexpr (XFORM) {
        const float a  = coef[k0 + k];
        const float bb = coef[256 + k0 + k];
        float t;
        t = fmaf(a, x0.x, bb); x0.x = t >= 0.f ? t : SLOPE * t;
        t = fmaf(a, x0.y, bb); x0.y = t >= 0.f ? t : SLOPE * t;
        t = fmaf(a, x0.z, bb); x0.z = t >= 0.f ? t : SLOPE * t;
        t = fmaf(a, x0.w, bb); x0.w = t >= 0.f ? t : SLOPE * t;
        t = fmaf(a, x1.x, bb); x1.x = t >= 0.f ? t : SLOPE * t;
        t = fmaf(a, x1.y, bb); x1.y = t >= 0.f ? t : SLOPE * t;
        t = fmaf(a, x1.z, bb); x1.z = t >= 0.f ? t : SLOPE * t;
        t = fmaf(a, x1.w, bb); x1.w = t >= 0.f ? t : SLOPE * t;
      }
      *(float4*)&Xt[k][nn]     = x0;
      *(float4*)&Xt[k][nn + 4] = x1;
    }
    __syncthreads();
    #pragma unroll
    for (int kk = 0; kk < BK; ++kk) {
      float4 av = *(const float4*)&Wt[kk][ty * 4];
      float4 bv = *(const float4*)&Xt[kk][tx * 4];
      acc[0][0] = fmaf(av.x, bv.x, acc[0][0]);
      acc[0][1] = fmaf(av.x, bv.y, acc[0][1]);
      acc[0][2] = fmaf(av.x, bv.z, acc[0][2]);
      acc[0][3] = fmaf(av.x, bv.w, acc[0][3]);
      acc[1][0] = fmaf(av.y, bv.x, acc[1][0]);
      acc[1][1] = fmaf(av.y, bv.y, acc[1][1]);
      acc[1][2] = fmaf(av.y, bv.z, acc[1][2]);
      acc[1][3] = fmaf(av.y, bv.w, acc[1][3]);
      acc[2][0] = fmaf(av.z, bv.x, acc[2][0]);
      acc[2][1] = fmaf(av.z, bv.y, acc[2][1]);
      acc[2][2] = fmaf(av.z, bv.z, acc[2][2]);
      acc[2][3] = fmaf(av.z, bv.w, acc[2][3]);
      acc[3][0] = fmaf(av.w, bv.x, acc[3][0]);
      acc[3][1] = fmaf(av.w, bv.y, acc[3][1]);
      acc[3][2] = fmaf(av.w, bv.z, acc[3][2]);
      acc[3][3] = fmaf(av.w, bv.w, acc[3][3]);
    }
    __syncthreads();
  }

  // bias, store, stats
  #pragma unroll
  for (int i = 0; i < 4; ++i) {
    const int o = o0 + ty * 4 + i;
    const float bi = bias[o];
    float4 v = make_float4(acc[i][0] + bi, acc[i][1] + bi, acc[i][2] + bi, acc[i][3] + bi);
    *(float4*)&Yout[((size_t)b * HCH + o) * N + n0 + tx * 4] = v;
    float s = v.x + v.y + v.z + v.w;
    float qq = v.x*v.x + v.y*v.y + v.z*v.z + v.w*v.w;
    #pragma unroll
    for (int off = 1; off < 16; off <<= 1) {
      s  += __shfl_xor(s, off);
      qq += __shfl_xor(qq, off);
    }
    if (tx == 0) {
      atomicAdd(&stats[o], s);
      atomicAdd(&stats[256 + o], qq);
    }
  }
}

// ---------------- BN finalize: stats -> per-channel (a, b) ----------------
__global__ void k_fin(const float* __restrict__ stats,
                      const float* __restrict__ gamma,
                      const float* __restrict__ beta,
                      float* __restrict__ coef) {
  const int c = threadIdx.x;
  const float mean = stats[c] / BN_CNT;
  const float var  = stats[256 + c] / BN_CNT - mean * mean;
  const float a    = gamma[c] / sqrtf(var + BN_EPS);
  coef[c]       = a;
  coef[256 + c] = fmaf(-a, mean, beta[c]);
}

// ---------------- final BN apply + LeakyReLU -> out ----------------
__global__ __launch_bounds__(256) void k_apply(const float* __restrict__ Y,
                                               const float* __restrict__ coef,
                                               float* __restrict__ out) {
  const size_t total = (size_t)B * HCH * N / 4;
  const float4* y4 = (const float4*)Y;
  float4* o4 = (float4*)out;
  for (size_t f = (size_t)blockIdx.x * blockDim.x + threadIdx.x; f < total;
       f += (size_t)gridDim.x * blockDim.x) {
    const int c = (int)((f / (N / 4)) % HCH);
    const float a = coef[c], bb = coef[256 + c];
    float4 v = y4[f];
    float t;
    t = fmaf(a, v.x, bb); v.x = t >= 0.f ? t : SLOPE * t;
    t = fmaf(a, v.y, bb); v.y = t >= 0.f ? t : SLOPE * t;
    t = fmaf(a, v.z, bb); v.z = t >= 0.f ? t : SLOPE * t;
    t = fmaf(a, v.w, bb); v.w = t >= 0.f ? t : SLOPE * t;
    o4[f] = v;
  }
}

extern "C" void kernel_launch(void* const* d_in, const int* in_sizes, int n_in,
                              void* d_out, int out_size, void* d_ws, size_t ws_size,
                              hipStream_t stream) {
  const float* xyz1    = (const float*)d_in[0];
  const float* xyz2    = (const float*)d_in[1];
  const float* points1 = (const float*)d_in[2];
  const float* points2 = (const float*)d_in[3];
  const float* W1      = (const float*)d_in[4];
  const float* b1      = (const float*)d_in[5];
  const float* gamma1  = (const float*)d_in[6];
  const float* beta1   = (const float*)d_in[7];
  const float* W2      = (const float*)d_in[8];
  const float* b2      = (const float*)d_in[9];
  const float* gamma2  = (const float*)d_in[10];
  const float* beta2   = (const float*)d_in[11];

  float* ws = (float*)d_ws;
  float* wgt    = ws;                                // B*N*3        = 98304
  int*   idx    = (int*)(ws + (size_t)B * N * 3);    // B*N*3        = 98304
  float* P2T    = ws + 2 * (size_t)B * N * 3;        // B*M*C2       = 2097152
  float* Xbuf   = P2T + (size_t)B * M * C2;          // B*CIN*N      = 12582912
  float* Y1     = Xbuf + (size_t)B * CIN * N;        // B*HCH*N      = 8388608
  float* Y2     = Xbuf;                              // alias: X dead after GEMM1
  float* stats1 = Y1 + (size_t)B * HCH * N;          // 512
  float* stats2 = stats1 + 512;                      // 512
  float* coef1  = stats2 + 512;                      // 512
  float* coef2  = coef1 + 512;                       // 512

  k_zero<<<4, 256, 0, stream>>>(stats1);  // zeroes stats1+stats2 (1024 floats)
  k_nn<<<B * (N / 64), 64, 0, stream>>>(xyz1, xyz2, wgt, idx);
  k_tr<<<dim3(M / 32, C2 / 32, B), 256, 0, stream>>>(points2, P2T);
  k_interp<<<dim3(N / 256, B), 256, 0, stream>>>(P2T, points1, wgt, idx, Xbuf);
  k_gemm<CIN, false><<<dim3(N / 64, HCH / 64, B), 256, 0, stream>>>(W1, b1, Xbuf, nullptr, Y1, stats1);
  k_fin<<<1, 256, 0, stream>>>(stats1, gamma1, beta1, coef1);
  k_gemm<HCH, true><<<dim3(N / 64, HCH / 64, B), 256, 0, stream>>>(W2, b2, Y1, coef1, Y2, stats2);
  k_fin<<<1, 256, 0, stream>>>(stats2, gamma2, beta2, coef2);
  k_apply<<<2048, 256, 0, stream>>>(Y2, coef2, (float*)d_out);
}

// Round 2
// 379.918 us; speedup vs baseline: 1.3374x; 1.3374x over previous
//
#include <hip/hip_runtime.h>
#include <math.h>

// Problem constants (from setup_inputs)
constexpr int B   = 4;
constexpr int N   = 8192;
constexpr int M   = 2048;
constexpr int C1  = 128;
constexpr int C2  = 256;
constexpr int HCH = 256;   // H
constexpr int CIN = 384;   // C2 + C1
constexpr float BN_EPS = 1e-5f;
constexpr float SLOPE  = 0.2f;
constexpr float BN_CNT = (float)(B * N);   // BN reduces over (B, N)

// ---------------- zero stats ----------------
__global__ void k_zero(float* __restrict__ stats) {
  int i = blockIdx.x * blockDim.x + threadIdx.x;
  if (i < 1024) stats[i] = 0.f;
}

// ---------------- three_nn + inverse-distance weights ----------------
// Block = 256 threads (4 waves). Wave w scans M-slice [w*512, w*512+512) for the
// block's 64 queries; partial top-3 kept in registers; 64-thread LDS merge.
// 512 blocks x 4 waves = 2048 waves (vs 512 before) and 4x shorter serial loop.
__global__ __launch_bounds__(256) void k_nn(const float* __restrict__ xyz1,
                                            const float* __restrict__ xyz2,
                                            float* __restrict__ wgt,
                                            int* __restrict__ idxo) {
  __shared__ float4 q[4][512];          // 32 KB: [slice][ref]
  __shared__ float  md[4][64][3];       // 3 KB: partial dists
  __shared__ int    mi[4][64][3];       // 3 KB: partial indices
  const int tid = threadIdx.x;
  const int b   = blockIdx.y;
  const int n0  = blockIdx.x * 64;

  // stage xyz2 batch slice (with precomputed squared norm in .w)
  const float* src = xyz2 + (size_t)b * M * 3;
  for (int i = tid; i < M; i += 256) {
    float x = src[i*3+0], y = src[i*3+1], z = src[i*3+2];
    q[i >> 9][i & 511] = make_float4(x, y, z, x*x + y*y + z*z);
  }
  __syncthreads();

  const int w = tid >> 6;               // slice / wave id
  const int t = tid & 63;               // query lane
  const int n = n0 + t;
  const float* p = xyz1 + ((size_t)b * N + n) * 3;
  const float px = p[0], py = p[1], pz = p[2];
  const float n1 = px*px + py*py + pz*pz;

  float d0 = 3.4e38f, d1 = 3.4e38f, d2 = 3.4e38f;
  int   j0 = 0, j1 = 0, j2 = 0;
  const float4* qs = q[w];
  #pragma unroll 4
  for (int r = 0; r < 512; ++r) {
    float4 c = qs[r];                   // wave-uniform address -> LDS broadcast
    float dot = px*c.x + py*c.y + pz*c.z;
    float d = fmaf(-2.f, dot, n1 + c.w);
    if (d < d2) {                        // strict < keeps lower index on ties
      int m = (w << 9) + r;
      if (d < d1) {
        if (d < d0) { d2 = d1; j2 = j1; d1 = d0; j1 = j0; d0 = d; j0 = m; }
        else        { d2 = d1; j2 = j1; d1 = d;  j1 = m; }
      } else        { d2 = d;  j2 = m; }
    }
  }
  md[w][t][0] = d0; md[w][t][1] = d1; md[w][t][2] = d2;
  mi[w][t][0] = j0; mi[w][t][1] = j1; mi[w][t][2] = j2;
  __syncthreads();

  // merge 12 candidates per query (slices in ascending-index order; strict <
  // insertion preserves top_k's lower-index-wins tie semantics)
  if (tid < 64) {
    float e0 = 3.4e38f, e1 = 3.4e38f, e2 = 3.4e38f;
    int   i0 = 0, i1 = 0, i2 = 0;
    #pragma unroll
    for (int s = 0; s < 4; ++s) {
      #pragma unroll
      for (int k = 0; k < 3; ++k) {
        float d = md[s][tid][k];
        int   m = mi[s][tid][k];
        if (d < e2) {
          if (d < e1) {
            if (d < e0) { e2 = e1; i2 = i1; e1 = e0; i1 = i0; e0 = d; i0 = m; }
            else        { e2 = e1; i2 = i1; e1 = d;  i1 = m; }
          } else        { e2 = d;  i2 = m; }
        }
      }
    }
    e0 = fmaxf(e0, 1e-10f); e1 = fmaxf(e1, 1e-10f); e2 = fmaxf(e2, 1e-10f);
    float r0 = 1.f / e0, r1 = 1.f / e1, r2 = 1.f / e2;
    float s  = r0 + r1 + r2;
    size_t base = ((size_t)b * N + n0 + tid) * 3;
    wgt[base+0] = r0 / s;  wgt[base+1] = r1 / s;  wgt[base+2] = r2 / s;
    idxo[base+0] = i0;     idxo[base+1] = i1;     idxo[base+2] = i2;
  }
}

// ---------------- transpose points2: (B,C2,M) -> (B,M,C2) ----------------
__global__ __launch_bounds__(256) void k_tr(const float* __restrict__ P2,
                                            float* __restrict__ P2T) {
  __shared__ float t[32][33];
  const int b  = blockIdx.z;
  const int m0 = blockIdx.x * 32;
  const int c0 = blockIdx.y * 32;
  const int tx = threadIdx.x & 31;
  const int ty = threadIdx.x >> 5;        // 0..7
  const float* src = P2 + (size_t)b * C2 * M;
  #pragma unroll
  for (int j = 0; j < 4; ++j)
    t[ty + j*8][tx] = src[(size_t)(c0 + ty + j*8) * M + m0 + tx];
  __syncthreads();
  float* dst = P2T + (size_t)b * M * C2;
  #pragma unroll
  for (int j = 0; j < 4; ++j)
    dst[(size_t)(m0 + ty + j*8) * C2 + c0 + tx] = t[tx][ty + j*8];
}

// ---------------- interpolate (from P2T) + concat points1 -> X (B,CIN,N) ----------------
__global__ __launch_bounds__(256) void k_interp(const float* __restrict__ P2T,
                                                const float* __restrict__ points1,
                                                const float* __restrict__ wgt,
                                                const int* __restrict__ idx,
                                                float* __restrict__ X) {
  const int b = blockIdx.y;
  const int n = blockIdx.x * 256 + threadIdx.x;
  const size_t base = (size_t)b * N + n;
  const int i0 = idx[base*3+0], i1 = idx[base*3+1], i2 = idx[base*3+2];
  const float w0 = wgt[base*3+0], w1 = wgt[base*3+1], w2 = wgt[base*3+2];
  const float4* r0 = (const float4*)(P2T + ((size_t)b * M + i0) * C2);
  const float4* r1 = (const float4*)(P2T + ((size_t)b * M + i1) * C2);
  const float4* r2 = (const float4*)(P2T + ((size_t)b * M + i2) * C2);
  float* Xb = X + (size_t)b * CIN * N + n;
  #pragma unroll 4
  for (int c4 = 0; c4 < C2/4; ++c4) {
    float4 a0 = r0[c4], a1 = r1[c4], a2 = r2[c4];
    Xb[(size_t)(c4*4+0) * N] = w0*a0.x + w1*a1.x + w2*a2.x;
    Xb[(size_t)(c4*4+1) * N] = w0*a0.y + w1*a1.y + w2*a2.y;
    Xb[(size_t)(c4*4+2) * N] = w0*a0.z + w1*a1.z + w2*a2.z;
    Xb[(size_t)(c4*4+3) * N] = w0*a0.w + w1*a1.w + w2*a2.w;
  }
  const float* p1 = points1 + (size_t)b * C1 * N + n;
  float* Xc = Xb + (size_t)C2 * N;
  #pragma unroll 4
  for (int c = 0; c < C1; ++c) Xc[(size_t)c * N] = p1[(size_t)c * N];
}

// ---------------- f32 tiled GEMM: Y(B,HCH,N) = W(HCH,K) @ Xin(B,K,N) + bias ----------------
// XFORM: apply per-channel BN affine + LeakyReLU (coef[c]=a, coef[256+c]=b) to Xin on load.
// Epilogue accumulates per-channel sum / sumsq into stats[0..255] / stats[256..511].
template <int K, bool XFORM>
__global__ __launch_bounds__(256) void k_gemm(const float* __restrict__ Wm,
                                              const float* __restrict__ bias,
                                              const float* __restrict__ Xin,
                                              const float* __restrict__ coef,
                                              float* __restrict__ Yout,
                                              float* __restrict__ stats) {
  constexpr int BK = 32;
  __shared__ float Wt[BK][64];
  __shared__ float Xt[BK][64];
  const int tid = threadIdx.x;
  const int tx = tid & 15, ty = tid >> 4;
  const int n0 = blockIdx.x * 64;
  const int o0 = blockIdx.y * 64;
  const int b  = blockIdx.z;
  const float* Xb = Xin + (size_t)b * K * N;

  float acc[4][4] = {};

  for (int k0 = 0; k0 < K; k0 += BK) {
    { // W tile 64x32, transpose into Wt[k][o]
      const int o  = tid >> 2;
      const int kk = (tid & 3) * 8;
      const float* wp = Wm + (size_t)(o0 + o) * K + k0 + kk;
      float4 wv0 = *(const float4*)(wp);
      float4 wv1 = *(const float4*)(wp + 4);
      Wt[kk+0][o] = wv0.x; Wt[kk+1][o] = wv0.y; Wt[kk+2][o] = wv0.z; Wt[kk+3][o] = wv0.w;
      Wt[kk+4][o] = wv1.x; Wt[kk+5][o] = wv1.y; Wt[kk+6][o] = wv1.z; Wt[kk+7][o] = wv1.w;
    }
    { // X tile 32x64
      const int k  = tid >> 3;
      const int nn = (tid & 7) * 8;
      const float* xp = Xb + (size_t)(k0 + k) * N + n0 + nn;
      float4 x0 = *(const float4*)(xp);
      float4 x1 = *(const float4*)(xp + 4);
      if constexpr (XFORM) {
        const float a  = coef[k0 + k];
        const float bb = coef[256 + k0 + k];
        float t;
        t = fmaf(a, x0.x, bb); x0.x = t >= 0.f ? t : SLOPE * t;
        t = fmaf(a, x0.y, bb); x0.y = t >= 0.f ? t : SLOPE * t;
        t = fmaf(a, x0.z, bb); x0.z = t >= 0.f ? t : SLOPE * t;
        t = fmaf(a, x0.w, bb); x0.w = t >= 0.f ? t : SLOPE * t;
        t = fmaf(a, x1.x, bb); x1.x = t >= 0.f ? t : SLOPE * t;
        t = fmaf(a, x1.y, bb); x1.y = t >= 0.f ? t : SLOPE * t;
        t = fmaf(a, x1.z, bb); x1.z = t >= 0.f ? t : SLOPE * t;
        t = fmaf(a, x1.w, bb); x1.w = t >= 0.f ? t : SLOPE * t;
      }
      *(float4*)&Xt[k][nn]     = x0;
      *(float4*)&Xt[k][nn + 4] = x1;
    }
    __syncthreads();
    #pragma unroll
    for (int kk = 0; kk < BK; ++kk) {
      float4 av = *(const float4*)&Wt[kk][ty * 4];
      float4 bv = *(const float4*)&Xt[kk][tx * 4];
      acc[0][0] = fmaf(av.x, bv.x, acc[0][0]);
      acc[0][1] = fmaf(av.x, bv.y, acc[0][1]);
      acc[0][2] = fmaf(av.x, bv.z, acc[0][2]);
      acc[0][3] = fmaf(av.x, bv.w, acc[0][3]);
      acc[1][0] = fmaf(av.y, bv.x, acc[1][0]);
      acc[1][1] = fmaf(av.y, bv.y, acc[1][1]);
      acc[1][2] = fmaf(av.y, bv.z, acc[1][2]);
      acc[1][3] = fmaf(av.y, bv.w, acc[1][3]);
      acc[2][0] = fmaf(av.z, bv.x, acc[2][0]);
      acc[2][1] = fmaf(av.z, bv.y, acc[2][1]);
      acc[2][2] = fmaf(av.z, bv.z, acc[2][2]);
      acc[2][3] = fmaf(av.z, bv.w, acc[2][3]);
      acc[3][0] = fmaf(av.w, bv.x, acc[3][0]);
      acc[3][1] = fmaf(av.w, bv.y, acc[3][1]);
      acc[3][2] = fmaf(av.w, bv.z, acc[3][2]);
      acc[3][3] = fmaf(av.w, bv.w, acc[3][3]);
    }
    __syncthreads();
  }

  // bias, store, stats
  #pragma unroll
  for (int i = 0; i < 4; ++i) {
    const int o = o0 + ty * 4 + i;
    const float bi = bias[o];
    float4 v = make_float4(acc[i][0] + bi, acc[i][1] + bi, acc[i][2] + bi, acc[i][3] + bi);
    *(float4*)&Yout[((size_t)b * HCH + o) * N + n0 + tx * 4] = v;
    float s = v.x + v.y + v.z + v.w;
    float qq = v.x*v.x + v.y*v.y + v.z*v.z + v.w*v.w;
    #pragma unroll
    for (int off = 1; off < 16; off <<= 1) {
      s  += __shfl_xor(s, off);
      qq += __shfl_xor(qq, off);
    }
    if (tx == 0) {
      atomicAdd(&stats[o], s);
      atomicAdd(&stats[256 + o], qq);
    }
  }
}

// ---------------- BN finalize: stats -> per-channel (a, b) ----------------
__global__ void k_fin(const float* __restrict__ stats,
                      const float* __restrict__ gamma,
                      const float* __restrict__ beta,
                      float* __restrict__ coef) {
  const int c = threadIdx.x;
  const float mean = stats[c] / BN_CNT;
  const float var  = stats[256 + c] / BN_CNT - mean * mean;
  const float a    = gamma[c] / sqrtf(var + BN_EPS);
  coef[c]       = a;
  coef[256 + c] = fmaf(-a, mean, beta[c]);
}

// ---------------- final BN apply + LeakyReLU -> out ----------------
__global__ __launch_bounds__(256) void k_apply(const float* __restrict__ Y,
                                               const float* __restrict__ coef,
                                               float* __restrict__ out) {
  const size_t total = (size_t)B * HCH * N / 4;
  const float4* y4 = (const float4*)Y;
  float4* o4 = (float4*)out;
  for (size_t f = (size_t)blockIdx.x * blockDim.x + threadIdx.x; f < total;
       f += (size_t)gridDim.x * blockDim.x) {
    const int c = (int)((f / (N / 4)) % HCH);
    const float a = coef[c], bb = coef[256 + c];
    float4 v = y4[f];
    float t;
    t = fmaf(a, v.x, bb); v.x = t >= 0.f ? t : SLOPE * t;
    t = fmaf(a, v.y, bb); v.y = t >= 0.f ? t : SLOPE * t;
    t = fmaf(a, v.z, bb); v.z = t >= 0.f ? t : SLOPE * t;
    t = fmaf(a, v.w, bb); v.w = t >= 0.f ? t : SLOPE * t;
    o4[f] = v;
  }
}

extern "C" void kernel_launch(void* const* d_in, const int* in_sizes, int n_in,
                              void* d_out, int out_size, void* d_ws, size_t ws_size,
                              hipStream_t stream) {
  const float* xyz1    = (const float*)d_in[0];
  const float* xyz2    = (const float*)d_in[1];
  const float* points1 = (const float*)d_in[2];
  const float* points2 = (const float*)d_in[3];
  const float* W1      = (const float*)d_in[4];
  const float* b1      = (const float*)d_in[5];
  const float* gamma1  = (const float*)d_in[6];
  const float* beta1   = (const float*)d_in[7];
  const float* W2      = (const float*)d_in[8];
  const float* b2      = (const float*)d_in[9];
  const float* gamma2  = (const float*)d_in[10];
  const float* beta2   = (const float*)d_in[11];

  float* ws = (float*)d_ws;
  float* wgt    = ws;                                // B*N*3        = 98304
  int*   idx    = (int*)(ws + (size_t)B * N * 3);    // B*N*3        = 98304
  float* P2T    = ws + 2 * (size_t)B * N * 3;        // B*M*C2       = 2097152
  float* Xbuf   = P2T + (size_t)B * M * C2;          // B*CIN*N      = 12582912
  float* Y1     = Xbuf + (size_t)B * CIN * N;        // B*HCH*N      = 8388608
  float* Y2     = Xbuf;                              // alias: X dead after GEMM1
  float* stats1 = Y1 + (size_t)B * HCH * N;          // 512
  float* stats2 = stats1 + 512;                      // 512
  float* coef1  = stats2 + 512;                      // 512
  float* coef2  = coef1 + 512;                       // 512

  k_zero<<<4, 256, 0, stream>>>(stats1);  // zeroes stats1+stats2 (1024 floats)
  k_nn<<<dim3(N / 64, B), 256, 0, stream>>>(xyz1, xyz2, wgt, idx);
  k_tr<<<dim3(M / 32, C2 / 32, B), 256, 0, stream>>>(points2, P2T);
  k_interp<<<dim3(N / 256, B), 256, 0, stream>>>(P2T, points1, wgt, idx, Xbuf);
  k_gemm<CIN, false><<<dim3(N / 64, HCH / 64, B), 256, 0, stream>>>(W1, b1, Xbuf, nullptr, Y1, stats1);
  k_fin<<<1, 256, 0, stream>>>(stats1, gamma1, beta1, coef1);
  k_gemm<HCH, true><<<dim3(N / 64, HCH / 64, B), 256, 0, stream>>>(W2, b2, Y1, coef1, Y2, stats2);
  k_fin<<<1, 256, 0, stream>>>(stats2, gamma2, beta2, coef2);
  k_apply<<<2048, 256, 0, stream>>>(Y2, coef2, (float*)d_out);
}